// Round 11
// baseline (501.778 us; speedup 1.0000x reference)
//
#include <hip/hip_runtime.h>
#include <hip/hip_cooperative_groups.h>

// ---------------- problem constants ----------------
#define N_ANCH 221184      // H*W*A = 128*192*9
#define HW     24576       // H*W
#define Wd     192
#define AA     9
#define TOPN   6000
#define POSTN  300
#define CAND_CAP 8192
#define NWORDS 94          // ceil(6016/64) words of suppression bits
#define NCHUNK 47          // 6016 / 128

typedef unsigned long long u64;

namespace cg = cooperative_groups;

// anchor widths/heights (== ws2/hs2 of the reference, exact small ints)
__device__ const float c_aw[9] = {184.f,368.f,736.f,128.f,256.f,512.f, 88.f,176.f,352.f};
__device__ const float c_ah[9] = { 96.f,192.f,384.f,128.f,256.f,512.f,176.f,352.f,704.f};

// shared box decode — used by select_kernel AND rank_scatter so the FP
// sequence (and thus every bit of the box) is identical in both places.
__device__ __forceinline__ float4 decode_box(int a, int cell,
                                             const float* __restrict__ deltas,
                                             float info0, float info1, float info2,
                                             bool* valid) {
    int h = cell / Wd;
    int w = cell - h * Wd;
    const float* db = deltas + (size_t)(4 * a) * HW + cell;
    float dx = db[0];
    float dy = db[HW];
    float dw = db[2 * HW];
    float dh = db[3 * HW];
    dw = fminf(fmaxf(dw, -10.f), 10.f);
    dh = fminf(fmaxf(dh, -10.f), 10.f);

    float ww = c_aw[a], hh = c_ah[a];
    float cx = 16.f * (float)w + 8.f;   // exact
    float cy = 16.f * (float)h + 8.f;   // exact

    float pcx = __fadd_rn(__fmul_rn(dx, ww), cx);
    float pcy = __fadd_rn(__fmul_rn(dy, hh), cy);
    float pw  = __fmul_rn(expf(dw), ww);
    float ph  = __fmul_rn(expf(dh), hh);
    float hpw = __fmul_rn(0.5f, pw);
    float hph = __fmul_rn(0.5f, ph);
    float x1 = __fsub_rn(pcx, hpw);
    float x2 = __fadd_rn(pcx, hpw);
    float y1 = __fsub_rn(pcy, hph);
    float y2 = __fadd_rn(pcy, hph);

    float xmax = __fsub_rn(info1, 1.f);
    float ymax = __fsub_rn(info0, 1.f);
    x1 = fminf(fmaxf(x1, 0.f), xmax);
    x2 = fminf(fmaxf(x2, 0.f), xmax);
    y1 = fminf(fmaxf(y1, 0.f), ymax);
    y2 = fminf(fmaxf(y2, 0.f), ymax);

    float msz = __fmul_rn(16.f, info2);
    *valid = (__fadd_rn(__fsub_rn(x2, x1), 1.f) >= msz) &&
             (__fadd_rn(__fsub_rn(y2, y1), 1.f) >= msz);
    return make_float4(x1, y1, x2, y2);
}

// zero-region sizes in u64 units (phase 0 of select_kernel)
#define ZA_U8 8328    // hist256(1024) + state(64) + cand(65536) = 66624 B
#define ZB_U8 96      // vmask 768 B
#define ZC_U8 128     // h2 1024 B

// Fused select: zero -> decode -> hist256 -> P -> h2 -> T -> compact, all in
// ONE cooperative launch. Each thread's key lives in a REGISTER across all
// phases — the old keys[] array (884 KB write + 2 full re-reads) and three
// dispatch gaps are eliminated. Bit-identical T/cand vs rounds 8-10.
// Cross-XCD visibility: atomics are device-coherent; plain-data handoffs
// across grid.sync use volatile (sc-flagged) accesses.
__global__ __launch_bounds__(256, 4) void select_kernel(
        const float* __restrict__ scores,
        const float* __restrict__ deltas,
        const float* __restrict__ iminfo,
        unsigned int* __restrict__ hist256,
        unsigned int* __restrict__ h2,
        unsigned int* __restrict__ state,
        u64* __restrict__ cand,
        u64* zA, u64* zB, u64* zC) {
    cg::grid_group grid = cg::this_grid();
    __shared__ unsigned int lh[256];
    __shared__ unsigned int sfx[256];
    __shared__ unsigned int sP, sRank, sT;
    const int t = threadIdx.x;
    const int i = blockIdx.x * 256 + t;

    // ---- phase 0: zero hist256+state+cand, vmask, h2 (volatile stores) ----
    if (i < ZA_U8) ((volatile u64*)zA)[i] = 0ull;
    else if (i < ZA_U8 + ZB_U8) ((volatile u64*)zB)[i - ZA_U8] = 0ull;
    else if (i < ZA_U8 + ZB_U8 + ZC_U8) ((volatile u64*)zC)[i - ZA_U8 - ZB_U8] = 0ull;

    // ---- decode (independent of zeroing; overlaps phase 0) ----
    int a = i / HW;
    int cell = i - a * HW;
    float score = scores[(AA + a) * HW + cell];
    bool valid;
    (void)decode_box(a, cell, deltas, iminfo[0], iminfo[1], iminfo[2], &valid);
    unsigned int sb = __float_as_uint(score);
    // flip to ordered-uint; invalid -> key of -inf (0x007FFFFF)
    unsigned int key = valid ? ((sb & 0x80000000u) ? ~sb : (sb | 0x80000000u))
                             : 0x007FFFFFu;
    grid.sync();

    // ---- phase 1: top-byte histogram (LDS-aggregated) ----
    lh[t] = 0u;
    __syncthreads();
    atomicAdd(&lh[key >> 24], 1u);
    __syncthreads();
    if (lh[t]) atomicAdd(&hist256[t], lh[t]);
    grid.sync();

    // ---- phase 2: suffix-scan hist256 -> P, rank; then second-byte hist ----
    sfx[t] = ((volatile unsigned int*)hist256)[t];
    __syncthreads();
    for (int d = 1; d < 256; d <<= 1) {
        unsigned int v = (t + d < 256) ? sfx[t + d] : 0u;
        __syncthreads();
        sfx[t] += v;
        __syncthreads();
    }
    {
        unsigned int ge = sfx[t];
        unsigned int gt = (t < 255) ? sfx[t + 1] : 0u;
        if (ge >= TOPN && gt < TOPN) { sP = (unsigned int)t; sRank = TOPN - gt; }
    }
    __syncthreads();
    unsigned int P = sP, rank = sRank;
    lh[t] = 0u;
    __syncthreads();
    if ((key >> 24) == P) atomicAdd(&lh[(key >> 16) & 0xFFu], 1u);
    __syncthreads();
    if (lh[t]) atomicAdd(&h2[t], lh[t]);
    grid.sync();

    // ---- phase 3: suffix-scan h2 -> T; compact keys >= T (register key) ----
    sfx[t] = ((volatile unsigned int*)h2)[t];
    __syncthreads();
    for (int d = 1; d < 256; d <<= 1) {
        unsigned int v = (t + d < 256) ? sfx[t + d] : 0u;
        __syncthreads();
        sfx[t] += v;
        __syncthreads();
    }
    {
        unsigned int ge = sfx[t];
        unsigned int gt = (t < 255) ? sfx[t + 1] : 0u;
        if (ge >= rank && gt < rank) sT = (P << 24) | ((unsigned int)t << 16);
    }
    __syncthreads();
    unsigned int T = sT;
    if (key >= T) {
        unsigned int pos = atomicAdd(&state[2], 1u);
        if (pos < CAND_CAP) {
            unsigned int aidx = (unsigned int)(cell * 9 + a);  // reference anchor index
            cand[pos] = ((u64)key << 32) | (u64)(~aidx);
        }
    }
}

// fused exact-rank + scatter. rank[i] = #{j : key_j > key_i}; keys distinct
// (index in low bits) -> rank == sorted position (score desc, index asc —
// lax.top_k order). 256 blocks, 8 threads per i (32 i's/block); j-loop is
// interleaved (jj = part + 8k) so each wave-instruction reads 8 CONSECUTIVE
// ulonglong2s (conflict-free, broadcast across the 8 i-groups).
__global__ __launch_bounds__(256) void rank_scatter_kernel(const u64* __restrict__ cand,
                                                           const float* __restrict__ deltas,
                                                           const float* __restrict__ iminfo,
                                                           float4* __restrict__ tb,
                                                           u64* __restrict__ vmask) {
    __shared__ u64 s[CAND_CAP];
    for (int j = threadIdx.x; j < CAND_CAP; j += 256) s[j] = cand[j];
    int part = threadIdx.x & 7;
    int i = blockIdx.x * 32 + (threadIdx.x >> 3);
    u64 k = cand[i];
    __syncthreads();
    const ulonglong2* sv = (const ulonglong2*)s;
    unsigned int cnt = 0;
    #pragma unroll 8
    for (int jj = part; jj < CAND_CAP / 2; jj += 8) {
        ulonglong2 v = sv[jj];
        cnt += (v.x > k) ? 1u : 0u;
        cnt += (v.y > k) ? 1u : 0u;
    }
    cnt += __shfl_xor(cnt, 1);
    cnt += __shfl_xor(cnt, 2);
    cnt += __shfl_xor(cnt, 4);
    if (part == 0 && k != 0ull && cnt < TOPN) {
        unsigned int aidx = ~((unsigned int)k);
        int a = (int)(aidx % 9u);
        int cell = (int)(aidx / 9u);
        bool valid;
        float4 box = decode_box(a, cell, deltas, iminfo[0], iminfo[1], iminfo[2], &valid);
        tb[cnt] = box;
        if ((unsigned int)(k >> 32) != 0x007FFFFFu)
            atomicOr(&vmask[cnt >> 6], 1ull << (cnt & 63));
    }
}

// suppression bit-matrix, upper-triangle word-blocks only.
__global__ __launch_bounds__(64) void nms_matrix_kernel(const float4* __restrict__ tb,
                                                        u64* __restrict__ mat) {
    if (blockIdx.x < blockIdx.y) return;
    __shared__ float4 cb[64];
    int t = threadIdx.x;
    int c0 = blockIdx.x * 64;
    int col = c0 + t;
    cb[t] = (col < TOPN) ? tb[col] : make_float4(0.f, 0.f, 0.f, 0.f);
    __syncthreads();
    int row = blockIdx.y * 64 + t;
    if (row >= TOPN) return;
    float4 rb = tb[row];
    float rA = (rb.z - rb.x) * (rb.w - rb.y);
    u64 mask = 0ull;
    for (int c = 0; c < 64; ++c) {
        if (c0 + c >= TOPN) break;
        float4 b = cb[c];
        float lx = fmaxf(rb.x, b.x), ly = fmaxf(rb.y, b.y);
        float rx = fminf(rb.z, b.z), ry = fminf(rb.w, b.w);
        float iw = fmaxf(rx - lx, 0.f), ih = fmaxf(ry - ly, 0.f);
        float inter = iw * ih;
        float bA = (b.z - b.x) * (b.w - b.y);
        float iou = inter / ((rA + bA) - inter);
        if (iou > 0.7f) mask |= (1ull << c);   // NaN compares false, as in numpy
    }
    mat[(size_t)row * NWORDS + blockIdx.x] = mask;
}

// 64-bit readlane with wave-uniform index (v_readlane — much cheaper than
// ds_bpermute-based __shfl).
__device__ __forceinline__ u64 rdl64(u64 v, int l) {
    unsigned int lo = (unsigned int)__builtin_amdgcn_readlane((int)(unsigned int)v, l);
    unsigned int hi = (unsigned int)__builtin_amdgcn_readlane((int)(unsigned int)(v >> 32), l);
    return ((u64)hi << 32) | (u64)lo;
}

// single-wave greedy scan, 128-box chunks (47 sequential steps). ROUND-0
// structure, verbatim — proven 66 µs / FETCH 114 KB / VGPR 36. Rounds 1-7
// established that every deeper pipeline (register or producer/consumer)
// loses to this on sync/spill/publish overhead.
//  - diagonal 128x128 bit-block prefetched ONE CHUNK AHEAD into registers
//  - in-chunk greedy: wave-uniform ALU + 4 readlanes per kept box
//  - propagation: lane w owns removal words w / 64+w; batched 8 kept deep
__global__ __launch_bounds__(64) void nms_scan_kernel(const u64* __restrict__ mat,
                                                      const u64* __restrict__ vmask,
                                                      const float4* __restrict__ tb,
                                                      float* __restrict__ out) {
    int lane = threadIdx.x;
    u64 r0 = ~vmask[lane];
    u64 r1 = (lane < NWORDS - 64) ? ~vmask[64 + lane] : ~0ull;
    __shared__ int kept[POSTN];
    int cnt = 0;

    u64 a0, a1, b0, b1;
    {
        ulonglong2 vA = *(const ulonglong2*)(mat + (size_t)lane * NWORDS);
        ulonglong2 vB = *(const ulonglong2*)(mat + (size_t)(64 + lane) * NWORDS);
        a0 = vA.x; a1 = vA.y; b0 = vB.x; b1 = vB.y;
    }
    for (int c = 0; c < NCHUNK; ++c) {
        u64 na0 = 0, na1 = 0, nb0 = 0, nb1 = 0;
        if (c + 1 < NCHUNK) {
            const u64* pA = mat + (size_t)((c + 1) * 128 + lane) * NWORDS + 2 * (c + 1);
            const u64* pB = mat + (size_t)((c + 1) * 128 + 64 + lane) * NWORDS + 2 * (c + 1);
            ulonglong2 vA = *(const ulonglong2*)pA;
            ulonglong2 vB = *(const ulonglong2*)pB;
            na0 = vA.x; na1 = vA.y; nb0 = vB.x; nb1 = vB.y;
        }
        int w2 = 2 * c;
        u64 s0 = (w2 < 64) ? rdl64(r0, w2) : rdl64(r1, w2 - 64);
        u64 s1 = (w2 + 1 < 64) ? rdl64(r0, w2 + 1) : rdl64(r1, w2 + 1 - 64);
        if ((s0 & s1) != ~0ull) {
            int base = c * 128;
            u64 rem0 = s0, rem1 = s1, k0 = 0ull, k1 = 0ull;
            while (cnt < POSTN) {
                int b;
                if (~rem0) b = __ffsll((u64)~rem0) - 1;
                else if (~rem1) b = 64 + __ffsll((u64)~rem1) - 1;
                else break;
                if (lane == 0) kept[cnt] = base + b;
                ++cnt;
                u64 w0, w1;
                if (b < 64) {
                    w0 = rdl64(a0, b); w1 = rdl64(a1, b);
                    k0 |= 1ull << b; rem0 |= 1ull << b;
                } else {
                    int bb = b - 64;
                    w0 = rdl64(b0, bb); w1 = rdl64(b1, bb);
                    k1 |= 1ull << bb; rem1 |= 1ull << bb;
                }
                rem0 |= w0; rem1 |= w1;
            }
            if (cnt >= POSTN) break;
            u64 f0 = 0ull, f1 = 0ull, m0 = k0, m1 = k1;
            while (m0 | m1) {
                int idxs[8];
                #pragma unroll
                for (int j = 0; j < 8; ++j) {
                    int b = -1;
                    if (m0) { b = __ffsll(m0) - 1; m0 &= m0 - 1; }
                    else if (m1) { b = 64 + __ffsll(m1) - 1; m1 &= m1 - 1; }
                    idxs[j] = b;
                }
                u64 v0[8], v1[8];
                #pragma unroll
                for (int j = 0; j < 8; ++j) {
                    v0[j] = 0ull; v1[j] = 0ull;
                    if (idxs[j] >= 0) {
                        const u64* row = mat + (size_t)(base + idxs[j]) * NWORDS;
                        v0[j] = row[lane];
                        if (lane < NWORDS - 64) v1[j] = row[64 + lane];
                    }
                }
                #pragma unroll
                for (int j = 0; j < 8; ++j) { f0 |= v0[j]; f1 |= v1[j]; }
            }
            r0 |= f0; r1 |= f1;
        }
        a0 = na0; a1 = na1; b0 = nb0; b1 = nb1;
    }

    for (int r = lane; r < POSTN; r += 64) {
        float4 b = make_float4(0.f, 0.f, 0.f, 0.f);
        if (r < cnt) b = tb[kept[r]];
        float* o = out + r * 5;
        o[0] = 0.f; o[1] = b.x; o[2] = b.y; o[3] = b.z; o[4] = b.w;
    }
}

// ---------------- host launcher ----------------
extern "C" void kernel_launch(void* const* d_in, const int* in_sizes, int n_in,
                              void* d_out, int out_size, void* d_ws, size_t ws_size,
                              hipStream_t stream) {
    const float* scores = (const float*)d_in[0];
    const float* deltas = (const float*)d_in[1];
    const float* iminfo = (const float*)d_in[2];
    float* out = (float*)d_out;

    char* ws = (char*)d_ws;
    // workspace layout (16B-aligned); keys array no longer exists (keys live
    // in registers inside select_kernel)
    unsigned int* hist256 = (unsigned int*)(ws + 884736);     // 256*4     = 1024
    unsigned int* state   = (unsigned int*)(ws + 885760);     // 64
    u64*          cand    = (u64*)(ws + 885824);              // 8192*8    = 65536
    float4*       tb      = (float4*)(ws + 951360);           // 6016*16   = 96256
    u64*          vmask   = (u64*)(ws + 1047616);             // 768
    u64*          mat     = (u64*)(ws + 1048384);             // 6016*94*8 = 4524032
    // h2 reuses mat's first 1 KB: its last read (select phase 3) precedes
    // nms_matrix's first write -> no extra workspace needed.
    unsigned int* h2      = (unsigned int*)(ws + 1048384);    // 256*4 = 1024

    u64* zA = (u64*)hist256;   // hist256+state+cand contiguous (66624 B)
    u64* zB = (u64*)vmask;
    u64* zC = (u64*)h2;

    const int NB = N_ANCH / 256;   // 864 exactly

    void* args[] = {
        (void*)&scores, (void*)&deltas, (void*)&iminfo,
        (void*)&hist256, (void*)&h2, (void*)&state, (void*)&cand,
        (void*)&zA, (void*)&zB, (void*)&zC
    };
    hipLaunchCooperativeKernel(reinterpret_cast<void*>(select_kernel),
                               dim3(NB), dim3(256), args, 0, stream);
    rank_scatter_kernel<<<CAND_CAP / 32, 256, 0, stream>>>(cand, deltas, iminfo, tb, vmask);
    nms_matrix_kernel<<<dim3(NWORDS, NWORDS), 64, 0, stream>>>(tb, mat);
    nms_scan_kernel<<<1, 64, 0, stream>>>(mat, vmask, tb, out);
}

// Round 12
// 268.321 us; speedup vs baseline: 1.8701x; 1.8701x over previous
//
#include <hip/hip_runtime.h>

// ---------------- problem constants ----------------
#define N_ANCH 221184      // H*W*A = 128*192*9
#define HW     24576       // H*W
#define Wd     192
#define AA     9
#define TOPN   6000
#define POSTN  300
#define CAND_CAP 8128      // was 8192; tail 376B of the cand slot now holds rowcnt
#define NWORDS 94          // ceil(6016/64) words of suppression bits
#define NCHUNK 47          // 6016 / 128

typedef unsigned long long u64;

// anchor widths/heights (== ws2/hs2 of the reference, exact small ints)
__device__ const float c_aw[9] = {184.f,368.f,736.f,128.f,256.f,512.f, 88.f,176.f,352.f};
__device__ const float c_ah[9] = { 96.f,192.f,384.f,128.f,256.f,512.f,176.f,352.f,704.f};

// shared box decode — used by decode_kernel AND rank_scatter so the FP
// sequence (and thus every bit of the box) is identical in both places.
__device__ __forceinline__ float4 decode_box(int a, int cell,
                                             const float* __restrict__ deltas,
                                             float info0, float info1, float info2,
                                             bool* valid) {
    int h = cell / Wd;
    int w = cell - h * Wd;
    const float* db = deltas + (size_t)(4 * a) * HW + cell;
    float dx = db[0];
    float dy = db[HW];
    float dw = db[2 * HW];
    float dh = db[3 * HW];
    dw = fminf(fmaxf(dw, -10.f), 10.f);
    dh = fminf(fmaxf(dh, -10.f), 10.f);

    float ww = c_aw[a], hh = c_ah[a];
    float cx = 16.f * (float)w + 8.f;   // exact
    float cy = 16.f * (float)h + 8.f;   // exact

    float pcx = __fadd_rn(__fmul_rn(dx, ww), cx);
    float pcy = __fadd_rn(__fmul_rn(dy, hh), cy);
    float pw  = __fmul_rn(expf(dw), ww);
    float ph  = __fmul_rn(expf(dh), hh);
    float hpw = __fmul_rn(0.5f, pw);
    float hph = __fmul_rn(0.5f, ph);
    float x1 = __fsub_rn(pcx, hpw);
    float x2 = __fadd_rn(pcx, hpw);
    float y1 = __fsub_rn(pcy, hph);
    float y2 = __fadd_rn(pcy, hph);

    float xmax = __fsub_rn(info1, 1.f);
    float ymax = __fsub_rn(info0, 1.f);
    x1 = fminf(fmaxf(x1, 0.f), xmax);
    x2 = fminf(fmaxf(x2, 0.f), xmax);
    y1 = fminf(fmaxf(y1, 0.f), ymax);
    y2 = fminf(fmaxf(y2, 0.f), ymax);

    float msz = __fmul_rn(16.f, info2);
    *valid = (__fadd_rn(__fsub_rn(x2, x1), 1.f) >= msz) &&
             (__fadd_rn(__fsub_rn(y2, y1), 1.f) >= msz);
    return make_float4(x1, y1, x2, y2);
}

// ------- init: zero hist256+state+cand+rowcnt (contiguous), vmask, h2 -----
#define ZA_F4 4164    // (1024 + 64 + 65536) / 16 — covers rowcnt in cand tail
#define ZB_F4 48      // 768 / 16
#define ZC_F4 64      // 1024 / 16  (h2, carved from mat base)
__global__ __launch_bounds__(256) void init_kernel(float4* zA, float4* zB,
                                                   float4* zC) {
    int t = blockIdx.x * 256 + threadIdx.x;
    float4 z = make_float4(0.f, 0.f, 0.f, 0.f);
    if (t < ZA_F4) zA[t] = z;
    else if (t < ZA_F4 + ZB_F4) zB[t - ZA_F4] = z;
    else if (t < ZA_F4 + ZB_F4 + ZC_F4) zC[t - ZA_F4 - ZB_F4] = z;
}

// thread t maps to (a = t/HW, cell = t%HW) so reads of scores/deltas are
// coalesced. Writes the 32-bit ordered key; builds the top-BYTE histogram
// LDS-aggregated (256 global atomics per block). ROUND-8 form — round 9
// proved per-key device atomics on a 64K hist are a 94 µs contention bomb.
__global__ __launch_bounds__(256) void decode_kernel(const float* __restrict__ scores,
                                                     const float* __restrict__ deltas,
                                                     const float* __restrict__ iminfo,
                                                     unsigned int* __restrict__ keys,
                                                     unsigned int* __restrict__ hist256) {
    __shared__ unsigned int lh[256];
    lh[threadIdx.x] = 0u;
    __syncthreads();
    int t = blockIdx.x * 256 + threadIdx.x;
    int a = t / HW;
    int cell = t - a * HW;
    float score = scores[(AA + a) * HW + cell];
    bool valid;
    (void)decode_box(a, cell, deltas, iminfo[0], iminfo[1], iminfo[2], &valid);
    unsigned int sb = __float_as_uint(score);
    // flip to ordered-uint; invalid -> key of -inf (0x007FFFFF)
    unsigned int key = valid ? ((sb & 0x80000000u) ? ~sb : (sb | 0x80000000u))
                             : 0x007FFFFFu;
    keys[t] = key;
    atomicAdd(&lh[key >> 24], 1u);
    __syncthreads();
    if (lh[threadIdx.x]) atomicAdd(&hist256[threadIdx.x], lh[threadIdx.x]);
}

// per-block suffix-scan of hist256 -> prefix byte P (and rank).
// Pure function of hist256 — every block computes the same values.
__device__ __forceinline__ void scanP(const unsigned int* __restrict__ hist256,
                                      unsigned int* sfx, unsigned int* sP,
                                      unsigned int* sRank, int t) {
    sfx[t] = hist256[t];
    __syncthreads();
    for (int d = 1; d < 256; d <<= 1) {
        unsigned int v = (t + d < 256) ? sfx[t + d] : 0u;
        __syncthreads();
        sfx[t] += v;
        __syncthreads();
    }
    unsigned int ge = sfx[t];
    unsigned int gt = (t < 255) ? sfx[t + 1] : 0u;
    if (ge >= TOPN && gt < TOPN) { *sP = (unsigned int)t; *sRank = TOPN - gt; }
    __syncthreads();
}

// parallel second-level histogram: 864 blocks; each block recomputes P from
// hist256 (1 KB, L2-hot), filters its 256 keys for top byte == P (~860
// matches grid-wide), LDS-aggregates their second byte, dumps nonzero
// counters to global h2 (~860 total device atomics — no contention).
__global__ __launch_bounds__(256) void hist2_kernel(const unsigned int* __restrict__ keys,
                                                    const unsigned int* __restrict__ hist256,
                                                    unsigned int* __restrict__ h2) {
    __shared__ unsigned int sfx[256];
    __shared__ unsigned int lh[256];
    __shared__ unsigned int sP, sRank;
    int t = threadIdx.x;
    lh[t] = 0u;
    scanP(hist256, sfx, &sP, &sRank, t);
    unsigned int P = sP;
    unsigned int k = keys[blockIdx.x * 256 + t];
    if ((k >> 24) == P) atomicAdd(&lh[(k >> 16) & 0xFFu], 1u);
    __syncthreads();
    if (lh[t]) atomicAdd(&h2[t], lh[t]);
}

// compact: per-block recompute P/rank (hist256) and T (h2 suffix), then
// take all keys >= T (boundary bucket fully included; ~6000+~430 < 8128).
__global__ __launch_bounds__(256) void compact_kernel(const unsigned int* __restrict__ keys,
                                                      const unsigned int* __restrict__ hist256,
                                                      const unsigned int* __restrict__ h2,
                                                      unsigned int* __restrict__ state,
                                                      u64* __restrict__ cand) {
    __shared__ unsigned int sfx[256];
    __shared__ unsigned int sP, sRank, sT;
    int t = threadIdx.x;
    scanP(hist256, sfx, &sP, &sRank, t);
    unsigned int P = sP, rank = sRank;
    __syncthreads();
    sfx[t] = h2[t];
    __syncthreads();
    for (int d = 1; d < 256; d <<= 1) {
        unsigned int v = (t + d < 256) ? sfx[t + d] : 0u;
        __syncthreads();
        sfx[t] += v;
        __syncthreads();
    }
    {
        unsigned int ge = sfx[t];
        unsigned int gt = (t < 255) ? sfx[t + 1] : 0u;
        if (ge >= rank && gt < rank) sT = (P << 24) | ((unsigned int)t << 16);
    }
    __syncthreads();
    unsigned int T = sT;
    int i = blockIdx.x * 256 + t;
    unsigned int k = keys[i];
    if (k >= T) {
        unsigned int pos = atomicAdd(&state[2], 1u);
        if (pos < CAND_CAP) {
            int a = i / HW;
            int cell = i - a * HW;
            unsigned int aidx = (unsigned int)(cell * 9 + a);  // reference anchor index
            cand[pos] = ((u64)k << 32) | (u64)(~aidx);
        }
    }
}

// fused exact-rank + scatter. rank[i] = #{j : key_j > key_i}; keys distinct
// (index in low bits) -> rank == sorted position (score desc, index asc —
// lax.top_k order). 254 blocks, 8 threads per i (32 i's/block); j-loop is
// interleaved (jj = part + 8k) so each wave-instruction reads 8 CONSECUTIVE
// ulonglong2s (conflict-free, broadcast across the 8 i-groups).
__global__ __launch_bounds__(256) void rank_scatter_kernel(const u64* __restrict__ cand,
                                                           const float* __restrict__ deltas,
                                                           const float* __restrict__ iminfo,
                                                           float4* __restrict__ tb,
                                                           u64* __restrict__ vmask) {
    __shared__ u64 s[CAND_CAP];
    for (int j = threadIdx.x; j < CAND_CAP; j += 256) s[j] = cand[j];
    int part = threadIdx.x & 7;
    int i = blockIdx.x * 32 + (threadIdx.x >> 3);
    u64 k = cand[i];
    __syncthreads();
    const ulonglong2* sv = (const ulonglong2*)s;
    unsigned int cnt = 0;
    #pragma unroll 8
    for (int jj = part; jj < CAND_CAP / 2; jj += 8) {
        ulonglong2 v = sv[jj];
        cnt += (v.x > k) ? 1u : 0u;
        cnt += (v.y > k) ? 1u : 0u;
    }
    cnt += __shfl_xor(cnt, 1);
    cnt += __shfl_xor(cnt, 2);
    cnt += __shfl_xor(cnt, 4);
    if (part == 0 && k != 0ull && cnt < TOPN) {
        unsigned int aidx = ~((unsigned int)k);
        int a = (int)(aidx % 9u);
        int cell = (int)(aidx / 9u);
        bool valid;
        float4 box = decode_box(a, cell, deltas, iminfo[0], iminfo[1], iminfo[2], &valid);
        tb[cnt] = box;
        if ((unsigned int)(k >> 32) != 0x007FFFFFu)
            atomicOr(&vmask[cnt >> 6], 1ull << (cnt & 63));
    }
}

// 64-bit readlane with wave-uniform index (v_readlane — much cheaper than
// ds_bpermute-based __shfl).
__device__ __forceinline__ u64 rdl64(u64 v, int l) {
    unsigned int lo = (unsigned int)__builtin_amdgcn_readlane((int)(unsigned int)v, l);
    unsigned int hi = (unsigned int)__builtin_amdgcn_readlane((int)(unsigned int)(v >> 32), l);
    return ((u64)hi << 32) | (u64)lo;
}

// FUSED NMS: suppression bit-matrix (producer blocks) + single-wave greedy
// scan (one consumer block) in ONE dispatch. The dependency is one-way:
//  - matrix block (x,y), x>=y: compute 64x64 IoU mask word; store with
//    AGENT-scope atomic stores (device-visible, no L2-flush storm), then one
//    RELEASE fetch_add on rowcnt[y]. Producers never wait -> no deadlock,
//    no co-residency assumption.
//  - scan block (the single block at blockIdx.y==NWORDS): acquire-polls
//    rowcnt[y] == NWORDS - y for the <=4 row-blocks the upcoming chunk
//    needs, then runs the proven round-0 scan body unchanged. Only ONE
//    spinner in the grid -> none of round-11's N-spinner collapse.
// Sub-diagonal blocks (x<y) stay unwritten: the scan tolerates that garbage
// (those bits only ever OR into already-decided columns), same as round 0.
__global__ __launch_bounds__(64) void nms_kernel(const float4* __restrict__ tb,
                                                 u64* __restrict__ mat,
                                                 const u64* __restrict__ vmask,
                                                 float* __restrict__ out,
                                                 unsigned int* __restrict__ rowcnt) {
    __shared__ float4 cb[64];
    __shared__ int kept[POSTN];
    const int t = threadIdx.x;

    if (blockIdx.y < NWORDS) {
        // ---------------- matrix producer ----------------
        if (blockIdx.x < blockIdx.y) return;
        int c0 = blockIdx.x * 64;
        int col = c0 + t;
        cb[t] = (col < TOPN) ? tb[col] : make_float4(0.f, 0.f, 0.f, 0.f);
        __syncthreads();
        int row = blockIdx.y * 64 + t;
        if (row < TOPN) {
            float4 rb = tb[row];
            float rA = (rb.z - rb.x) * (rb.w - rb.y);
            u64 mask = 0ull;
            for (int c = 0; c < 64; ++c) {
                if (c0 + c >= TOPN) break;
                float4 b = cb[c];
                float lx = fmaxf(rb.x, b.x), ly = fmaxf(rb.y, b.y);
                float rx = fminf(rb.z, b.z), ry = fminf(rb.w, b.w);
                float iw = fmaxf(rx - lx, 0.f), ih = fmaxf(ry - ly, 0.f);
                float inter = iw * ih;
                float bA = (b.z - b.x) * (b.w - b.y);
                float iou = inter / ((rA + bA) - inter);
                if (iou > 0.7f) mask |= (1ull << c);   // NaN compares false
            }
            __hip_atomic_store(&mat[(size_t)row * NWORDS + blockIdx.x], mask,
                               __ATOMIC_RELAXED, __HIP_MEMORY_SCOPE_AGENT);
        }
        __syncthreads();   // drains the stores (waitcnt before barrier)
        if (t == 0)
            __hip_atomic_fetch_add(&rowcnt[blockIdx.y], 1u,
                                   __ATOMIC_RELEASE, __HIP_MEMORY_SCOPE_AGENT);
        return;
    }
    if (blockIdx.x != 0) return;

    // ---------------- scan consumer (round-0 body + row gates) ----------
    int lane = t;
    u64 r0 = ~vmask[lane];
    u64 r1 = (lane < NWORDS - 64) ? ~vmask[64 + lane] : ~0ull;
    int cnt = 0;
    int gated = 0;   // rows [0, gated) verified complete

    // gate rows 0..3 (initial diag of chunk 0 + chunk 1 prefetch)
    for (; gated <= 3; ++gated) {
        unsigned int tgt = (unsigned int)(NWORDS - gated);
        while (__hip_atomic_load(&rowcnt[gated], __ATOMIC_ACQUIRE,
                                 __HIP_MEMORY_SCOPE_AGENT) < tgt) {}
    }

    u64 a0, a1, b0, b1;
    {
        ulonglong2 vA = *(const ulonglong2*)(mat + (size_t)lane * NWORDS);
        ulonglong2 vB = *(const ulonglong2*)(mat + (size_t)(64 + lane) * NWORDS);
        a0 = vA.x; a1 = vA.y; b0 = vB.x; b1 = vB.y;
    }
    for (int c = 0; c < NCHUNK; ++c) {
        // gate rows needed by this iteration: propagation (2c,2c+1) and
        // next-chunk diag prefetch (2c+2,2c+3)
        int hi = 2 * c + 3;
        if (hi > NWORDS - 1) hi = NWORDS - 1;
        for (; gated <= hi; ++gated) {
            unsigned int tgt = (unsigned int)(NWORDS - gated);
            while (__hip_atomic_load(&rowcnt[gated], __ATOMIC_ACQUIRE,
                                     __HIP_MEMORY_SCOPE_AGENT) < tgt) {}
        }

        u64 na0 = 0, na1 = 0, nb0 = 0, nb1 = 0;
        if (c + 1 < NCHUNK) {
            const u64* pA = mat + (size_t)((c + 1) * 128 + lane) * NWORDS + 2 * (c + 1);
            const u64* pB = mat + (size_t)((c + 1) * 128 + 64 + lane) * NWORDS + 2 * (c + 1);
            ulonglong2 vA = *(const ulonglong2*)pA;
            ulonglong2 vB = *(const ulonglong2*)pB;
            na0 = vA.x; na1 = vA.y; nb0 = vB.x; nb1 = vB.y;
        }
        int w2 = 2 * c;
        u64 s0 = (w2 < 64) ? rdl64(r0, w2) : rdl64(r1, w2 - 64);
        u64 s1 = (w2 + 1 < 64) ? rdl64(r0, w2 + 1) : rdl64(r1, w2 + 1 - 64);
        if ((s0 & s1) != ~0ull) {
            int base = c * 128;
            u64 rem0 = s0, rem1 = s1, k0 = 0ull, k1 = 0ull;
            while (cnt < POSTN) {
                int b;
                if (~rem0) b = __ffsll((u64)~rem0) - 1;
                else if (~rem1) b = 64 + __ffsll((u64)~rem1) - 1;
                else break;
                if (lane == 0) kept[cnt] = base + b;
                ++cnt;
                u64 w0, w1;
                if (b < 64) {
                    w0 = rdl64(a0, b); w1 = rdl64(a1, b);
                    k0 |= 1ull << b; rem0 |= 1ull << b;
                } else {
                    int bb = b - 64;
                    w0 = rdl64(b0, bb); w1 = rdl64(b1, bb);
                    k1 |= 1ull << bb; rem1 |= 1ull << bb;
                }
                rem0 |= w0; rem1 |= w1;
            }
            if (cnt >= POSTN) break;
            u64 f0 = 0ull, f1 = 0ull, m0 = k0, m1 = k1;
            while (m0 | m1) {
                int idxs[8];
                #pragma unroll
                for (int j = 0; j < 8; ++j) {
                    int b = -1;
                    if (m0) { b = __ffsll(m0) - 1; m0 &= m0 - 1; }
                    else if (m1) { b = 64 + __ffsll(m1) - 1; m1 &= m1 - 1; }
                    idxs[j] = b;
                }
                u64 v0[8], v1[8];
                #pragma unroll
                for (int j = 0; j < 8; ++j) {
                    v0[j] = 0ull; v1[j] = 0ull;
                    if (idxs[j] >= 0) {
                        const u64* row = mat + (size_t)(base + idxs[j]) * NWORDS;
                        v0[j] = row[lane];
                        if (lane < NWORDS - 64) v1[j] = row[64 + lane];
                    }
                }
                #pragma unroll
                for (int j = 0; j < 8; ++j) { f0 |= v0[j]; f1 |= v1[j]; }
            }
            r0 |= f0; r1 |= f1;
        }
        a0 = na0; a1 = na1; b0 = nb0; b1 = nb1;
    }

    for (int r = lane; r < POSTN; r += 64) {
        float4 b = make_float4(0.f, 0.f, 0.f, 0.f);
        if (r < cnt) b = tb[kept[r]];
        float* o = out + r * 5;
        o[0] = 0.f; o[1] = b.x; o[2] = b.y; o[3] = b.z; o[4] = b.w;
    }
}

// ---------------- host launcher ----------------
extern "C" void kernel_launch(void* const* d_in, const int* in_sizes, int n_in,
                              void* d_out, int out_size, void* d_ws, size_t ws_size,
                              hipStream_t stream) {
    const float* scores = (const float*)d_in[0];
    const float* deltas = (const float*)d_in[1];
    const float* iminfo = (const float*)d_in[2];
    float* out = (float*)d_out;

    char* ws = (char*)d_ws;
    // workspace layout (16B-aligned), total 5,572,416 bytes
    unsigned int* keys    = (unsigned int*)(ws + 0);          // 221184*4  = 884736
    unsigned int* hist256 = (unsigned int*)(ws + 884736);     // 256*4     = 1024
    unsigned int* state   = (unsigned int*)(ws + 885760);     // 64
    u64*          cand    = (u64*)(ws + 885824);              // 8128*8    = 65024
    unsigned int* rowcnt  = (unsigned int*)(ws + 885824 + 65024); // 94*4 = 376 (cand tail; zeroed by init's ZA range)
    float4*       tb      = (float4*)(ws + 951360);           // 6016*16   = 96256
    u64*          vmask   = (u64*)(ws + 1047616);             // 768
    u64*          mat     = (u64*)(ws + 1048384);             // 6016*94*8 = 4524032
    // h2 reuses mat's first 1 KB: its last read (compact) precedes the fused
    // nms kernel's first mat write -> no extra workspace needed.
    unsigned int* h2      = (unsigned int*)(ws + 1048384);    // 256*4 = 1024

    const int NB = N_ANCH / 256;   // 864 exactly

    init_kernel<<<17, 256, 0, stream>>>((float4*)hist256, (float4*)vmask,
                                        (float4*)h2);
    decode_kernel<<<NB, 256, 0, stream>>>(scores, deltas, iminfo, keys, hist256);
    hist2_kernel<<<NB, 256, 0, stream>>>(keys, hist256, h2);
    compact_kernel<<<NB, 256, 0, stream>>>(keys, hist256, h2, state, cand);
    rank_scatter_kernel<<<CAND_CAP / 32, 256, 0, stream>>>(cand, deltas, iminfo, tb, vmask);
    nms_kernel<<<dim3(NWORDS, NWORDS + 1), 64, 0, stream>>>(tb, mat, vmask, out, rowcnt);
}

// Round 13
// 240.530 us; speedup vs baseline: 2.0861x; 1.1155x over previous
//
#include <hip/hip_runtime.h>

// ---------------- problem constants ----------------
#define N_ANCH 221184      // H*W*A = 128*192*9
#define HW     24576       // H*W
#define Wd     192
#define AA     9
#define TOPN   6000
#define POSTN  300
#define CAND_CAP 8192
#define NWORDS 94          // ceil(6016/64) words of suppression bits
#define NCHUNK 47          // 6016 / 128
#define NBUCK  32768       // 15-bit select buckets
#define BSHIFT 17          // key >> BSHIFT = bucket

typedef unsigned long long u64;

// anchor widths/heights (== ws2/hs2 of the reference, exact small ints)
__device__ const float c_aw[9] = {184.f,368.f,736.f,128.f,256.f,512.f, 88.f,176.f,352.f};
__device__ const float c_ah[9] = { 96.f,192.f,384.f,128.f,256.f,512.f,176.f,352.f,704.f};

// bucket -> storage index rotation: value-adjacent hot buckets scatter across
// cache lines/L2 channels. r9 lesson: without this, the [0.5,1) buckets pack
// into ~8 lines and ~14K serialized atomic adds per line cost ~94 us.
__device__ __forceinline__ unsigned int rot15(unsigned int b) {
    return ((b << 7) | (b >> 8)) & 0x7FFFu;
}

// shared box decode — used by decode_kernel AND rank_scatter so the FP
// sequence (and thus every bit of the box) is identical in both places.
__device__ __forceinline__ float4 decode_box(int a, int cell,
                                             const float* __restrict__ deltas,
                                             float info0, float info1, float info2,
                                             bool* valid) {
    int h = cell / Wd;
    int w = cell - h * Wd;
    const float* db = deltas + (size_t)(4 * a) * HW + cell;
    float dx = db[0];
    float dy = db[HW];
    float dw = db[2 * HW];
    float dh = db[3 * HW];
    dw = fminf(fmaxf(dw, -10.f), 10.f);
    dh = fminf(fmaxf(dh, -10.f), 10.f);

    float ww = c_aw[a], hh = c_ah[a];
    float cx = 16.f * (float)w + 8.f;   // exact
    float cy = 16.f * (float)h + 8.f;   // exact

    float pcx = __fadd_rn(__fmul_rn(dx, ww), cx);
    float pcy = __fadd_rn(__fmul_rn(dy, hh), cy);
    float pw  = __fmul_rn(expf(dw), ww);
    float ph  = __fmul_rn(expf(dh), hh);
    float hpw = __fmul_rn(0.5f, pw);
    float hph = __fmul_rn(0.5f, ph);
    float x1 = __fsub_rn(pcx, hpw);
    float x2 = __fadd_rn(pcx, hpw);
    float y1 = __fsub_rn(pcy, hph);
    float y2 = __fadd_rn(pcy, hph);

    float xmax = __fsub_rn(info1, 1.f);
    float ymax = __fsub_rn(info0, 1.f);
    x1 = fminf(fmaxf(x1, 0.f), xmax);
    x2 = fminf(fmaxf(x2, 0.f), xmax);
    y1 = fminf(fmaxf(y1, 0.f), ymax);
    y2 = fminf(fmaxf(y2, 0.f), ymax);

    float msz = __fmul_rn(16.f, info2);
    *valid = (__fadd_rn(__fsub_rn(x2, x1), 1.f) >= msz) &&
             (__fadd_rn(__fsub_rn(y2, y1), 1.f) >= msz);
    return make_float4(x1, y1, x2, y2);
}

// ---------------- init: zero hist32k (128 KB) only ----------------
// (state/cand/vmask zeroing folded into decode — they're first used in
// LATER dispatches; hist32k is atomically accumulated by decode itself so
// it must be zero before decode starts.)
__global__ __launch_bounds__(256) void init_kernel(float4* zH) {
    int t = blockIdx.x * 256 + threadIdx.x;
    zH[t] = make_float4(0.f, 0.f, 0.f, 0.f);   // grid sized exactly 8192 f4
}

// thread t maps to (a = t/HW, cell = t%HW) so reads of scores/deltas are
// coalesced. Writes the 32-bit ordered key; builds a 15-bit-bucket histogram
// LDS-aggregated (packed u16 pairs, 64 KB LDS) and flushes <=2 atomics per
// nonzero packed word to the ROTATED global layout (r9-safe). Also zeroes
// state+cand (zA) and vmask (zB) for the later dispatches.
__global__ __launch_bounds__(256) void decode_kernel(const float* __restrict__ scores,
                                                     const float* __restrict__ deltas,
                                                     const float* __restrict__ iminfo,
                                                     unsigned int* __restrict__ keys,
                                                     unsigned int* __restrict__ hist,
                                                     float4* __restrict__ zA,
                                                     float4* __restrict__ zB) {
    __shared__ unsigned int lhp[NBUCK / 2];   // 64 KB: bucket pairs (lo=2i, hi=2i+1)
    for (int i = threadIdx.x; i < NBUCK / 2; i += 256) lhp[i] = 0u;

    int t = blockIdx.x * 256 + threadIdx.x;
    // folded zeroing: state(64B)+cand(65536B) = 4100 f4; vmask = 48 f4
    float4 z = make_float4(0.f, 0.f, 0.f, 0.f);
    if (t < 4100) zA[t] = z;
    else if (t < 4148) zB[t - 4100] = z;

    int a = t / HW;
    int cell = t - a * HW;
    float score = scores[(AA + a) * HW + cell];
    bool valid;
    (void)decode_box(a, cell, deltas, iminfo[0], iminfo[1], iminfo[2], &valid);
    unsigned int sb = __float_as_uint(score);
    // flip to ordered-uint; invalid -> key of -inf (0x007FFFFF)
    unsigned int key = valid ? ((sb & 0x80000000u) ? ~sb : (sb | 0x80000000u))
                             : 0x007FFFFFu;
    keys[t] = key;
    __syncthreads();   // LDS zero complete
    unsigned int b = key >> BSHIFT;
    atomicAdd(&lhp[b >> 1], 1u << ((b & 1u) << 4));   // halves can't overflow (<=256/block)
    __syncthreads();
    for (int i = threadIdx.x; i < NBUCK / 2; i += 256) {
        unsigned int v = lhp[i];
        if (v) {
            unsigned int lo = v & 0xFFFFu, hi = v >> 16;
            if (lo) atomicAdd(&hist[rot15(2u * i)], lo);
            if (hi) atomicAdd(&hist[rot15(2u * i + 1u)], hi);
        }
    }
}

// compact: each block independently recomputes the threshold T from hist32k
// (deterministic pure function -> identical across blocks; replaces the old
// hist2+midselect dispatches), then appends all keys >= T to cand.
// T-selection: two hierarchical suffix-scans (256 ranges of 128 buckets,
// then the 128 buckets of the crossing range), boundary bucket fully
// included. Selected count on this input ~6000+<=1728 < CAND_CAP.
__global__ __launch_bounds__(256) void compact_kernel(const unsigned int* __restrict__ keys,
                                                      const unsigned int* __restrict__ hist,
                                                      unsigned int* __restrict__ state,
                                                      u64* __restrict__ cand) {
    __shared__ unsigned int sfx[256];
    __shared__ unsigned int sC, sGt, sT;
    int t = threadIdx.x;

    // level 1: partial sums of contiguous 128-bucket ranges (rotated reads)
    unsigned int part = 0;
    int rbase = t * 128;
    for (int j = 0; j < 128; ++j) part += hist[rot15((unsigned int)(rbase + j))];
    sfx[t] = part;
    __syncthreads();
    for (int d = 1; d < 256; d <<= 1) {
        unsigned int v = (t + d < 256) ? sfx[t + d] : 0u;
        __syncthreads();
        sfx[t] += v;
        __syncthreads();
    }
    {
        unsigned int ge = sfx[t];
        unsigned int gt = (t < 255) ? sfx[t + 1] : 0u;
        if (ge >= TOPN && gt < TOPN) { sC = (unsigned int)t; sGt = gt; }
    }
    __syncthreads();
    unsigned int cbase = sC * 128u;
    unsigned int gtA = sGt;
    // level 2: suffix-scan the crossing range's 128 buckets
    unsigned int e = (t < 128) ? hist[rot15(cbase + (unsigned int)t)] : 0u;
    __syncthreads();
    sfx[t] = e;
    __syncthreads();
    for (int d = 1; d < 256; d <<= 1) {
        unsigned int v = (t + d < 256) ? sfx[t + d] : 0u;
        __syncthreads();
        sfx[t] += v;
        __syncthreads();
    }
    {
        unsigned int ge = sfx[t] + gtA;
        unsigned int gt = ((t < 255) ? sfx[t + 1] : 0u) + gtA;
        if (t < 128 && ge >= TOPN && gt < TOPN)
            sT = (cbase + (unsigned int)t) << BSHIFT;
    }
    __syncthreads();
    unsigned int T = sT;

    int i = blockIdx.x * 256 + t;
    unsigned int k = keys[i];
    if (k >= T) {
        unsigned int pos = atomicAdd(&state[2], 1u);
        if (pos < CAND_CAP) {
            int a = i / HW;
            int cell = i - a * HW;
            unsigned int aidx = (unsigned int)(cell * 9 + a);  // reference anchor index
            cand[pos] = ((u64)k << 32) | (u64)(~aidx);
        }
    }
}

// fused exact-rank + scatter. rank[i] = #{j : key_j > key_i}; keys distinct
// (index in low bits) -> rank == sorted position (score desc, index asc —
// lax.top_k order). 256 blocks, 8 threads per i (32 i's/block); j-loop is
// interleaved (jj = part + 8k) so each wave-instruction reads 8 CONSECUTIVE
// ulonglong2s (conflict-free, broadcast across the 8 i-groups).
__global__ __launch_bounds__(256) void rank_scatter_kernel(const u64* __restrict__ cand,
                                                           const float* __restrict__ deltas,
                                                           const float* __restrict__ iminfo,
                                                           float4* __restrict__ tb,
                                                           u64* __restrict__ vmask) {
    __shared__ u64 s[CAND_CAP];
    for (int j = threadIdx.x; j < CAND_CAP; j += 256) s[j] = cand[j];
    int part = threadIdx.x & 7;
    int i = blockIdx.x * 32 + (threadIdx.x >> 3);
    u64 k = cand[i];
    __syncthreads();
    const ulonglong2* sv = (const ulonglong2*)s;
    unsigned int cnt = 0;
    #pragma unroll 8
    for (int jj = part; jj < CAND_CAP / 2; jj += 8) {
        ulonglong2 v = sv[jj];
        cnt += (v.x > k) ? 1u : 0u;
        cnt += (v.y > k) ? 1u : 0u;
    }
    cnt += __shfl_xor(cnt, 1);
    cnt += __shfl_xor(cnt, 2);
    cnt += __shfl_xor(cnt, 4);
    if (part == 0 && k != 0ull && cnt < TOPN) {
        unsigned int aidx = ~((unsigned int)k);
        int a = (int)(aidx % 9u);
        int cell = (int)(aidx / 9u);
        bool valid;
        float4 box = decode_box(a, cell, deltas, iminfo[0], iminfo[1], iminfo[2], &valid);
        tb[cnt] = box;
        if ((unsigned int)(k >> 32) != 0x007FFFFFu)
            atomicOr(&vmask[cnt >> 6], 1ull << (cnt & 63));
    }
}

// suppression bit-matrix, upper-triangle word-blocks only.
__global__ __launch_bounds__(64) void nms_matrix_kernel(const float4* __restrict__ tb,
                                                        u64* __restrict__ mat) {
    if (blockIdx.x < blockIdx.y) return;
    __shared__ float4 cb[64];
    int t = threadIdx.x;
    int c0 = blockIdx.x * 64;
    int col = c0 + t;
    cb[t] = (col < TOPN) ? tb[col] : make_float4(0.f, 0.f, 0.f, 0.f);
    __syncthreads();
    int row = blockIdx.y * 64 + t;
    if (row >= TOPN) return;
    float4 rb = tb[row];
    float rA = (rb.z - rb.x) * (rb.w - rb.y);
    u64 mask = 0ull;
    for (int c = 0; c < 64; ++c) {
        if (c0 + c >= TOPN) break;
        float4 b = cb[c];
        float lx = fmaxf(rb.x, b.x), ly = fmaxf(rb.y, b.y);
        float rx = fminf(rb.z, b.z), ry = fminf(rb.w, b.w);
        float iw = fmaxf(rx - lx, 0.f), ih = fmaxf(ry - ly, 0.f);
        float inter = iw * ih;
        float bA = (b.z - b.x) * (b.w - b.y);
        float iou = inter / ((rA + bA) - inter);
        if (iou > 0.7f) mask |= (1ull << c);   // NaN compares false, as in numpy
    }
    mat[(size_t)row * NWORDS + blockIdx.x] = mask;
}

// 64-bit readlane with wave-uniform index (v_readlane — much cheaper than
// ds_bpermute-based __shfl).
__device__ __forceinline__ u64 rdl64(u64 v, int l) {
    unsigned int lo = (unsigned int)__builtin_amdgcn_readlane((int)(unsigned int)v, l);
    unsigned int hi = (unsigned int)__builtin_amdgcn_readlane((int)(unsigned int)(v >> 32), l);
    return ((u64)hi << 32) | (u64)lo;
}

// single-wave greedy scan, 128-box chunks (47 sequential steps). ROUND-0
// structure, verbatim — proven 66 µs / FETCH 114 KB / VGPR 36. Rounds 1-7
// established that every deeper pipeline (register or producer/consumer)
// loses to this on sync/spill/publish overhead; rounds 11-12 established
// that intra-dispatch fusion of matrix+scan pays uncached-store costs.
__global__ __launch_bounds__(64) void nms_scan_kernel(const u64* __restrict__ mat,
                                                      const u64* __restrict__ vmask,
                                                      const float4* __restrict__ tb,
                                                      float* __restrict__ out) {
    int lane = threadIdx.x;
    u64 r0 = ~vmask[lane];
    u64 r1 = (lane < NWORDS - 64) ? ~vmask[64 + lane] : ~0ull;
    __shared__ int kept[POSTN];
    int cnt = 0;

    u64 a0, a1, b0, b1;
    {
        ulonglong2 vA = *(const ulonglong2*)(mat + (size_t)lane * NWORDS);
        ulonglong2 vB = *(const ulonglong2*)(mat + (size_t)(64 + lane) * NWORDS);
        a0 = vA.x; a1 = vA.y; b0 = vB.x; b1 = vB.y;
    }
    for (int c = 0; c < NCHUNK; ++c) {
        u64 na0 = 0, na1 = 0, nb0 = 0, nb1 = 0;
        if (c + 1 < NCHUNK) {
            const u64* pA = mat + (size_t)((c + 1) * 128 + lane) * NWORDS + 2 * (c + 1);
            const u64* pB = mat + (size_t)((c + 1) * 128 + 64 + lane) * NWORDS + 2 * (c + 1);
            ulonglong2 vA = *(const ulonglong2*)pA;
            ulonglong2 vB = *(const ulonglong2*)pB;
            na0 = vA.x; na1 = vA.y; nb0 = vB.x; nb1 = vB.y;
        }
        int w2 = 2 * c;
        u64 s0 = (w2 < 64) ? rdl64(r0, w2) : rdl64(r1, w2 - 64);
        u64 s1 = (w2 + 1 < 64) ? rdl64(r0, w2 + 1) : rdl64(r1, w2 + 1 - 64);
        if ((s0 & s1) != ~0ull) {
            int base = c * 128;
            u64 rem0 = s0, rem1 = s1, k0 = 0ull, k1 = 0ull;
            while (cnt < POSTN) {
                int b;
                if (~rem0) b = __ffsll((u64)~rem0) - 1;
                else if (~rem1) b = 64 + __ffsll((u64)~rem1) - 1;
                else break;
                if (lane == 0) kept[cnt] = base + b;
                ++cnt;
                u64 w0, w1;
                if (b < 64) {
                    w0 = rdl64(a0, b); w1 = rdl64(a1, b);
                    k0 |= 1ull << b; rem0 |= 1ull << b;
                } else {
                    int bb = b - 64;
                    w0 = rdl64(b0, bb); w1 = rdl64(b1, bb);
                    k1 |= 1ull << bb; rem1 |= 1ull << bb;
                }
                rem0 |= w0; rem1 |= w1;
            }
            if (cnt >= POSTN) break;
            u64 f0 = 0ull, f1 = 0ull, m0 = k0, m1 = k1;
            while (m0 | m1) {
                int idxs[8];
                #pragma unroll
                for (int j = 0; j < 8; ++j) {
                    int b = -1;
                    if (m0) { b = __ffsll(m0) - 1; m0 &= m0 - 1; }
                    else if (m1) { b = 64 + __ffsll(m1) - 1; m1 &= m1 - 1; }
                    idxs[j] = b;
                }
                u64 v0[8], v1[8];
                #pragma unroll
                for (int j = 0; j < 8; ++j) {
                    v0[j] = 0ull; v1[j] = 0ull;
                    if (idxs[j] >= 0) {
                        const u64* row = mat + (size_t)(base + idxs[j]) * NWORDS;
                        v0[j] = row[lane];
                        if (lane < NWORDS - 64) v1[j] = row[64 + lane];
                    }
                }
                #pragma unroll
                for (int j = 0; j < 8; ++j) { f0 |= v0[j]; f1 |= v1[j]; }
            }
            r0 |= f0; r1 |= f1;
        }
        a0 = na0; a1 = na1; b0 = nb0; b1 = nb1;
    }

    for (int r = lane; r < POSTN; r += 64) {
        float4 b = make_float4(0.f, 0.f, 0.f, 0.f);
        if (r < cnt) b = tb[kept[r]];
        float* o = out + r * 5;
        o[0] = 0.f; o[1] = b.x; o[2] = b.y; o[3] = b.z; o[4] = b.w;
    }
}

// ---------------- host launcher ----------------
extern "C" void kernel_launch(void* const* d_in, const int* in_sizes, int n_in,
                              void* d_out, int out_size, void* d_ws, size_t ws_size,
                              hipStream_t stream) {
    const float* scores = (const float*)d_in[0];
    const float* deltas = (const float*)d_in[1];
    const float* iminfo = (const float*)d_in[2];
    float* out = (float*)d_out;

    char* ws = (char*)d_ws;
    // workspace layout (16B-aligned), total 5,572,416 bytes
    unsigned int* keys    = (unsigned int*)(ws + 0);          // 221184*4  = 884736
    unsigned int* state   = (unsigned int*)(ws + 885760);     // 64
    u64*          cand    = (u64*)(ws + 885824);              // 8192*8    = 65536
    float4*       tb      = (float4*)(ws + 951360);           // 6016*16   = 96256
    u64*          vmask   = (u64*)(ws + 1047616);             // 768
    u64*          mat     = (u64*)(ws + 1048384);             // 6016*94*8 = 4524032
    // hist32k reuses mat's first 128 KB: its last read (compact) precedes
    // nms_matrix's first write -> no extra workspace needed.
    unsigned int* hist32k = (unsigned int*)(ws + 1048384);    // 32768*4 = 131072

    const int NB = N_ANCH / 256;   // 864 exactly

    init_kernel<<<32, 256, 0, stream>>>((float4*)hist32k);    // 8192 f4 exactly
    decode_kernel<<<NB, 256, 0, stream>>>(scores, deltas, iminfo, keys, hist32k,
                                          (float4*)(ws + 885760),   // state+cand
                                          (float4*)vmask);
    compact_kernel<<<NB, 256, 0, stream>>>(keys, hist32k, state, cand);
    rank_scatter_kernel<<<CAND_CAP / 32, 256, 0, stream>>>(cand, deltas, iminfo, tb, vmask);
    nms_matrix_kernel<<<dim3(NWORDS, NWORDS), 64, 0, stream>>>(tb, mat);
    nms_scan_kernel<<<1, 64, 0, stream>>>(mat, vmask, tb, out);
}